// Round 4
// baseline (135.914 us; speedup 1.0000x reference)
//
#include <hip/hip_runtime.h>
#include <hip/hip_bf16.h>

#define B_   16
#define LQ_  2048
#define LK_  2048
#define D_   256
#define DV_  256
#define MINF -1.0e30f

typedef __bf16 bf16x8_t __attribute__((ext_vector_type(8)));
typedef short  s16x8    __attribute__((ext_vector_type(8)));
typedef short  s16x4    __attribute__((ext_vector_type(4)));
typedef float  f32x4    __attribute__((ext_vector_type(4)));

__device__ __forceinline__ unsigned short f2bf(float f) {
  unsigned int u = __builtin_bit_cast(unsigned int, f);
  u += 0x7fffu + ((u >> 16) & 1u);   // RNE (finite inputs)
  return (unsigned short)(u >> 16);
}

__device__ __forceinline__ s16x8 pack8(float4 a, float4 b) {
  s16x8 r;
  r[0] = (short)f2bf(a.x); r[1] = (short)f2bf(a.y);
  r[2] = (short)f2bf(a.z); r[3] = (short)f2bf(a.w);
  r[4] = (short)f2bf(b.x); r[5] = (short)f2bf(b.y);
  r[6] = (short)f2bf(b.z); r[7] = (short)f2bf(b.w);
  return r;
}

__device__ __forceinline__ void glds16(const unsigned short* g, unsigned short* l) {
  __builtin_amdgcn_global_load_lds(
      (const __attribute__((address_space(1))) unsigned int*)g,
      (__attribute__((address_space(3))) unsigned int*)l, 16, 0, 0);
}

// ---------- prepass: K -> bf16, row-major, chunk-XOR pre-swizzled ----------
__global__ __launch_bounds__(256) void prep_k(const float* __restrict__ K,
                                              unsigned short* __restrict__ wsK) {
  int gid = blockIdx.x * 256 + threadIdx.x;
  int gr = gid >> 5;
  int c  = gid & 31;
  const float* src = K + ((size_t)gr << 8) + c * 8;
  float4 a = *(const float4*)(src);
  float4 b = *(const float4*)(src + 4);
  *(s16x8*)(wsK + ((size_t)gr << 8) + ((c ^ (gr & 7)) << 3)) = pack8(a, b);
}

// ---------- prepass: V -> bf16, transposed per 64-key tile, 8-chunk-XOR ----
__global__ __launch_bounds__(256) void prep_v(const float* __restrict__ V,
                                              unsigned short* __restrict__ wsV) {
  __shared__ unsigned short t[256 * 72];
  const int tid = threadIdx.x;
  const float* src = V + (size_t)blockIdx.x * 64 * 256;
  #pragma unroll
  for (int i = 0; i < 16; ++i) {
    int idx = i * 256 + tid;
    int k   = idx >> 6;
    int dv0 = (idx & 63) * 4;
    float4 x = *(const float4*)(src + k * 256 + dv0);
    t[(dv0 + 0) * 72 + k] = f2bf(x.x);
    t[(dv0 + 1) * 72 + k] = f2bf(x.y);
    t[(dv0 + 2) * 72 + k] = f2bf(x.z);
    t[(dv0 + 3) * 72 + k] = f2bf(x.w);
  }
  __syncthreads();
  unsigned short* dst = wsV + (size_t)blockIdx.x * 16384;
  #pragma unroll
  for (int i = 0; i < 8; ++i) {
    int idx = i * 256 + tid;
    int dv = idx >> 3;
    int ch = idx & 7;
    s16x8 v = *(const s16x8*)(&t[dv * 72 + ch * 8]);
    *(s16x8*)(dst + dv * 64 + ((ch ^ (dv & 7)) << 3)) = v;
  }
}

// ---------- main v4: 8 waves, QB=128 (32 q/wave), KB=64 k-split ----------
// LDS map (shorts): K dbuf [0, 32768), V dbuf [32768, 65536), P [65536, 75776)
__global__ __launch_bounds__(512, 2) void attn_fwd4(
    const float* __restrict__ Q, const unsigned short* __restrict__ wsK,
    const unsigned short* __restrict__ wsV, const int* __restrict__ VL,
    float* __restrict__ O) {
  __shared__ __align__(16) unsigned short lds_all[75776];   // 151552 B

  const int tid  = threadIdx.x;
  const int wid  = tid >> 6;
  const int lane = tid & 63;
  const int l15  = lane & 15;
  const int lg   = lane >> 4;
  const int rq   = wid & 3;        // q sub-tile (32 rows)
  const int kh   = wid >> 2;       // k-half of 64-key tile

  const int bid = blockIdx.x;
  const int b   = bid >> 4;        // 16 q-tiles of 128 per batch
  const int qt  = bid & 15;

  int n_k = (VL[1] == 0) ? VL[2 * b] : VL[b];
  if (n_k < 1) n_k = 1;
  if (n_k > LK_) n_k = LK_;
  const int nt = (n_k + 63) >> 6;

  const int qbase = qt * 128 + rq * 32;

  // Q fragments (B-operand): qf[qc][dk] = Q[qbase+qc*16+l15][dk*32+lg*8 ..+8]
  s16x8 qf[2][8];
  #pragma unroll
  for (int qc = 0; qc < 2; ++qc) {
    const float* qp = Q + ((size_t)b * LQ_ + qbase + qc * 16 + l15) * D_ + lg * 8;
    #pragma unroll
    for (int dk = 0; dk < 8; ++dk) {
      float4 a = *(const float4*)(qp + dk * 32);
      float4 c = *(const float4*)(qp + dk * 32 + 4);
      qf[qc][dk] = pack8(a, c);
    }
  }

  f32x4 o[2][16];
  #pragma unroll
  for (int qc = 0; qc < 2; ++qc)
    #pragma unroll
    for (int c = 0; c < 16; ++c) o[qc][c] = (f32x4){0.f, 0.f, 0.f, 0.f};
  float m[2] = {MINF, MINF}, l[2] = {0.f, 0.f};

  const unsigned short* kbw = wsK + (size_t)b * LK_ * D_;
  const unsigned short* vbw = wsV + (size_t)b * LK_ * DV_;
  unsigned short* pw = &lds_all[65536 + wid * 1280];   // [32 q][40] bf16

#define STAGE(buf, t) do {                                                    \
    const unsigned short* ks_ = kbw + (size_t)(t) * 16384;                    \
    const unsigned short* vs_ = vbw + (size_t)(t) * 16384;                    \
    _Pragma("unroll")                                                         \
    for (int p = 0; p < 4; ++p) {                                             \
      int cu = p * 512 + wid * 64;                                            \
      glds16(ks_ + (size_t)(cu + lane) * 8, &lds_all[(buf) * 16384 + cu * 8]);\
      glds16(vs_ + (size_t)(cu + lane) * 8,                                   \
             &lds_all[32768 + (buf) * 16384 + cu * 8]);                       \
    }                                                                         \
  } while (0)

  STAGE(0, 0);
  __syncthreads();

  for (int t = 0; t < nt; ++t) {
    const int cur = t & 1;
    if (t + 1 < nt) STAGE(cur ^ 1, t + 1);

    // ---- S^T = K Q^T over this wave's 32-key window, 2 qc sub-tiles ----
    const unsigned short* kl = &lds_all[cur * 16384];
    f32x4 s[2][2];
    __builtin_amdgcn_s_setprio(1);
    #pragma unroll
    for (int kc = 0; kc < 2; ++kc) {
      int krow = kh * 32 + kc * 16 + l15;
      int sw = (krow & 7) << 3;
      const unsigned short* base = kl + krow * 256;
      f32x4 a0 = (f32x4){0.f, 0.f, 0.f, 0.f};
      f32x4 a1 = (f32x4){0.f, 0.f, 0.f, 0.f};
      #pragma unroll
      for (int dk = 0; dk < 8; ++dk) {
        s16x8 kf = *(const s16x8*)(base + ((dk * 32 + lg * 8) ^ sw));
        a0 = __builtin_amdgcn_mfma_f32_16x16x32_bf16(
            __builtin_bit_cast(bf16x8_t, kf),
            __builtin_bit_cast(bf16x8_t, qf[0][dk]), a0, 0, 0, 0);
        a1 = __builtin_amdgcn_mfma_f32_16x16x32_bf16(
            __builtin_bit_cast(bf16x8_t, kf),
            __builtin_bit_cast(bf16x8_t, qf[1][dk]), a1, 0, 0, 0);
      }
      s[kc][0] = a0;
      s[kc][1] = a1;
    }
    __builtin_amdgcn_s_setprio(0);

    // ---- scale + key mask (rows = keys) ----
    #pragma unroll
    for (int kc = 0; kc < 2; ++kc) {
      int gk = t * 64 + kh * 32 + kc * 16 + lg * 4;
      #pragma unroll
      for (int qc = 0; qc < 2; ++qc)
        #pragma unroll
        for (int j = 0; j < 4; ++j)
          s[kc][qc][j] = (gk + j < n_k) ? s[kc][qc][j] * 0.0625f : MINF;
    }

    // ---- online softmax per qc (q lane-local = l15), defer-max THR=8 ----
    float pm[2];
    #pragma unroll
    for (int qc = 0; qc < 2; ++qc) {
      float v = fmaxf(fmaxf(s[0][qc][0], s[0][qc][1]),
                      fmaxf(s[0][qc][2], s[0][qc][3]));
      v = fmaxf(v, fmaxf(fmaxf(s[1][qc][0], s[1][qc][1]),
                         fmaxf(s[1][qc][2], s[1][qc][3])));
      v = fmaxf(v, __shfl_xor(v, 16, 64));
      v = fmaxf(v, __shfl_xor(v, 32, 64));
      pm[qc] = v;
    }
    if (__any((pm[0] > m[0] + 8.0f) || (pm[1] > m[1] + 8.0f))) {
      #pragma unroll
      for (int qc = 0; qc < 2; ++qc) {
        float mn = fmaxf(m[qc], pm[qc]);
        float sc = __expf(m[qc] - mn);   // first tile: exp(-huge)=0
        m[qc] = mn; l[qc] *= sc;
        #pragma unroll
        for (int c = 0; c < 16; ++c) o[qc][c] = o[qc][c] * sc;
      }
    }
    #pragma unroll
    for (int qc = 0; qc < 2; ++qc) {
      float p[2][4];
      #pragma unroll
      for (int kc = 0; kc < 2; ++kc)
        #pragma unroll
        for (int j = 0; j < 4; ++j)
          p[kc][j] = __expf(s[kc][qc][j] - m[qc]);
      float ps = ((p[0][0] + p[0][1]) + (p[0][2] + p[0][3]))
               + ((p[1][0] + p[1][1]) + (p[1][2] + p[1][3]));
      ps += __shfl_xor(ps, 16, 64);
      ps += __shfl_xor(ps, 32, 64);
      l[qc] += ps;
      // store P^T fragment rows: [q=qc*16+l15][k' = kc*16+lg*4 ..+4]
      #pragma unroll
      for (int kc = 0; kc < 2; ++kc) {
        s16x4 w;
        w[0] = (short)f2bf(p[kc][0]); w[1] = (short)f2bf(p[kc][1]);
        w[2] = (short)f2bf(p[kc][2]); w[3] = (short)f2bf(p[kc][3]);
        *(s16x4*)(pw + (qc * 16 + l15) * 40 + kc * 16 + lg * 4) = w;
      }
    }

    // ---- P^T B-fragments (same-wave LDS round-trip) ----
    s16x8 pb[2];
    #pragma unroll
    for (int qc = 0; qc < 2; ++qc)
      pb[qc] = *(const s16x8*)(pw + (qc * 16 + l15) * 40 + lg * 8);

    // ---- O^T += V^T P^T over this wave's 32 keys ----
    const unsigned short* vl_ = &lds_all[32768 + cur * 16384];
    __builtin_amdgcn_s_setprio(1);
    #pragma unroll
    for (int c = 0; c < 16; ++c) {
      int dv = c * 16 + l15;
      s16x8 vf = *(const s16x8*)(vl_ + dv * 64 + (((kh * 4 + lg) ^ (dv & 7)) << 3));
      o[0][c] = __builtin_amdgcn_mfma_f32_16x16x32_bf16(
          __builtin_bit_cast(bf16x8_t, vf),
          __builtin_bit_cast(bf16x8_t, pb[0]), o[0][c], 0, 0, 0);
      o[1][c] = __builtin_amdgcn_mfma_f32_16x16x32_bf16(
          __builtin_bit_cast(bf16x8_t, vf),
          __builtin_bit_cast(bf16x8_t, pb[1]), o[1][c], 0, 0, 0);
    }
    __builtin_amdgcn_s_setprio(0);

    __syncthreads();   // buffer reuse + prefetch drain
  }

  // ---- merge k-halves: waves (rq, kh=1) publish, (rq, kh=0) combine ----
  // overlay per rq: [32 q][260 f32] + m at 8320+q, l at 8352+q (8448 f32 region)
  float* mo = (float*)lds_all + rq * 8448;
  if (kh == 1) {
    #pragma unroll
    for (int qc = 0; qc < 2; ++qc) {
      #pragma unroll
      for (int c = 0; c < 16; ++c)
        *(f32x4*)(mo + (qc * 16 + l15) * 260 + c * 16 + lg * 4) = o[qc][c];
      mo[8320 + qc * 16 + l15] = m[qc];   // 4 lg lanes dup-write (benign)
      mo[8352 + qc * 16 + l15] = l[qc];
    }
  }
  __syncthreads();
  if (kh == 0) {
    #pragma unroll
    for (int qc = 0; qc < 2; ++qc) {
      float mb = mo[8320 + qc * 16 + l15];
      float lb = mo[8352 + qc * 16 + l15];
      float M  = fmaxf(m[qc], mb);
      float sa = __expf(m[qc] - M), sb = __expf(mb - M);
      float invL = 1.0f / (sa * l[qc] + sb * lb);
      float* ob = O + ((size_t)b * LQ_ + qbase + qc * 16 + l15) * DV_;
      #pragma unroll
      for (int c = 0; c < 16; ++c) {
        int dvb = c * 16 + lg * 4;
        f32x4 mr = *(const f32x4*)(mo + (qc * 16 + l15) * 260 + dvb);
        f32x4 r;
        #pragma unroll
        for (int j = 0; j < 4; ++j) r[j] = (sa * o[qc][c][j] + sb * mr[j]) * invL;
        *(f32x4*)(ob + dvb) = r;
      }
    }
  }
#undef STAGE
}

// ---------- fallback (round-1 kernel, used if ws too small) ----------
__global__ __launch_bounds__(256) void attn_fwd(
    const float* __restrict__ Q, const float* __restrict__ K,
    const float* __restrict__ V, const int* __restrict__ VL,
    float* __restrict__ O) {
  __shared__ __align__(16) unsigned short lds_k[64 * D_];
  __shared__ __align__(16) unsigned short lds_v[DV_ * 64];
  __shared__ __align__(16) unsigned short lds_p[4][16 * 64];

  const int tid  = threadIdx.x;
  const int wid  = tid >> 6;
  const int lane = tid & 63;
  const int l15  = lane & 15;
  const int lg   = lane >> 4;
  const int bid = blockIdx.x;
  const int b   = bid >> 5;
  const int qt  = bid & 31;

  int n_k = (VL[1] == 0) ? VL[2 * b] : VL[b];
  if (n_k < 1) n_k = 1;
  if (n_k > LK_) n_k = LK_;

  const int qbase = qt * 64 + wid * 16;
  s16x8 qf[8];
  {
    const float* qp = Q + ((size_t)b * LQ_ + qbase + l15) * D_ + lg * 8;
    #pragma unroll
    for (int dk = 0; dk < 8; ++dk) {
      float4 a = *(const float4*)(qp + dk * 32);
      float4 c = *(const float4*)(qp + dk * 32 + 4);
      qf[dk] = pack8(a, c);
    }
  }
  f32x4 o[16];
  #pragma unroll
  for (int c = 0; c < 16; ++c) o[c] = (f32x4){0.f, 0.f, 0.f, 0.f};
  float m[4]    = {-INFINITY, -INFINITY, -INFINITY, -INFINITY};
  float lsum[4] = {0.f, 0.f, 0.f, 0.f};
  const float* kb = K + (size_t)b * LK_ * D_;
  const float* vb = V + (size_t)b * LK_ * DV_;
  const int nt = (n_k + 63) / 64;

  for (int kt = 0; kt < nt; ++kt) {
    __syncthreads();
    {
      const float* src = kb + (size_t)kt * 64 * D_;
      #pragma unroll
      for (int p = 0; p < 8; ++p) {
        int e = (p * 256 + tid) * 8;
        int r = e >> 8;
        int d = e & 255;
        float4 a = *(const float4*)(src + e);
        float4 c = *(const float4*)(src + e + 4);
        *(s16x8*)(&lds_k[r * 256 + (d ^ ((r & 7) << 3))]) = pack8(a, c);
      }
    }
    {
      const float* src = vb + (size_t)kt * 64 * DV_;
      #pragma unroll
      for (int p = 0; p < 2; ++p) {
        int item = p * 256 + tid;
        int k0  = (item >> 5) * 4;
        int dv0 = (item & 31) * 8;
        float va[4][8];
        #pragma unroll
        for (int r = 0; r < 4; ++r) {
          float4 x = *(const float4*)(src + (k0 + r) * DV_ + dv0);
          float4 y = *(const float4*)(src + (k0 + r) * DV_ + dv0 + 4);
          va[r][0]=x.x; va[r][1]=x.y; va[r][2]=x.z; va[r][3]=x.w;
          va[r][4]=y.x; va[r][5]=y.y; va[r][6]=y.z; va[r][7]=y.w;
        }
        #pragma unroll
        for (int i = 0; i < 8; ++i) {
          int dv = dv0 + i;
          s16x4 w;
          w[0]=(short)f2bf(va[0][i]); w[1]=(short)f2bf(va[1][i]);
          w[2]=(short)f2bf(va[2][i]); w[3]=(short)f2bf(va[3][i]);
          *(s16x4*)(&lds_v[dv * 64 + (k0 ^ ((dv & 7) << 3))]) = w;
        }
      }
    }
    __syncthreads();

    f32x4 s[4];
    #pragma unroll
    for (int kc = 0; kc < 4; ++kc) {
      f32x4 acc = (f32x4){0.f, 0.f, 0.f, 0.f};
      int krow = kc * 16 + l15;
      int sw = (krow & 7) << 3;
      #pragma unroll
      for (int dk = 0; dk < 8; ++dk) {
        s16x8 kf = *(const s16x8*)(&lds_k[krow * 256 + ((dk * 32 + lg * 8) ^ sw)]);
        acc = __builtin_amdgcn_mfma_f32_16x16x32_bf16(
            __builtin_bit_cast(bf16x8_t, qf[dk]),
            __builtin_bit_cast(bf16x8_t, kf), acc, 0, 0, 0);
      }
      s[kc] = acc;
    }
    #pragma unroll
    for (int kc = 0; kc < 4; ++kc) {
      int gk = kt * 64 + kc * 16 + l15;
      #pragma unroll
      for (int j = 0; j < 4; ++j) {
        float v = s[kc][j] * 0.0625f;
        s[kc][j] = (gk < n_k) ? v : -INFINITY;
      }
    }
    float pm[4];
    #pragma unroll
    for (int j = 0; j < 4; ++j)
      pm[j] = fmaxf(fmaxf(s[0][j], s[1][j]), fmaxf(s[2][j], s[3][j]));
    #pragma unroll
    for (int off = 1; off < 16; off <<= 1) {
      #pragma unroll
      for (int j = 0; j < 4; ++j)
        pm[j] = fmaxf(pm[j], __shfl_xor(pm[j], off, 64));
    }
    float sc[4];
    #pragma unroll
    for (int j = 0; j < 4; ++j) {
      float mn = fmaxf(m[j], pm[j]);
      sc[j] = __expf(m[j] - mn);
      m[j] = mn;
    }
    float psum[4] = {0.f, 0.f, 0.f, 0.f};
    #pragma unroll
    for (int kc = 0; kc < 4; ++kc) {
      #pragma unroll
      for (int j = 0; j < 4; ++j) {
        float p = __expf(s[kc][j] - m[j]);
        psum[j] += p;
        int r = lg * 4 + j;
        lds_p[wid][r * 64 + ((kc * 16 + l15) ^ ((r & 7) << 3))] = f2bf(p);
      }
    }
    #pragma unroll
    for (int off = 1; off < 16; off <<= 1) {
      #pragma unroll
      for (int j = 0; j < 4; ++j)
        psum[j] += __shfl_xor(psum[j], off, 64);
    }
    #pragma unroll
    for (int j = 0; j < 4; ++j) lsum[j] = lsum[j] * sc[j] + psum[j];
    #pragma unroll
    for (int c = 0; c < 16; ++c) {
      #pragma unroll
      for (int j = 0; j < 4; ++j) o[c][j] *= sc[j];
    }
    s16x8 pa[2];
    #pragma unroll
    for (int kk = 0; kk < 2; ++kk)
      pa[kk] = *(const s16x8*)(&lds_p[wid][l15 * 64 + ((kk * 32 + lg * 8) ^ ((l15 & 7) << 3))]);
    #pragma unroll
    for (int c = 0; c < 16; ++c) {
      #pragma unroll
      for (int kk = 0; kk < 2; ++kk) {
        int dv = c * 16 + l15;
        s16x8 vf = *(const s16x8*)(&lds_v[dv * 64 + ((kk * 32 + lg * 8) ^ ((dv & 7) << 3))]);
        o[c] = __builtin_amdgcn_mfma_f32_16x16x32_bf16(
            __builtin_bit_cast(bf16x8_t, pa[kk]),
            __builtin_bit_cast(bf16x8_t, vf), o[c], 0, 0, 0);
      }
    }
  }
  float inv[4];
  #pragma unroll
  for (int j = 0; j < 4; ++j) inv[j] = 1.0f / lsum[j];
  float* ob = O + ((size_t)b * LQ_ + qbase) * DV_;
  #pragma unroll
  for (int c = 0; c < 16; ++c) {
    #pragma unroll
    for (int j = 0; j < 4; ++j) {
      int r = lg * 4 + j;
      ob[(size_t)r * DV_ + c * 16 + l15] = o[c][j] * inv[j];
    }
  }
}

extern "C" void kernel_launch(void* const* d_in, const int* in_sizes, int n_in,
                              void* d_out, int out_size, void* d_ws, size_t ws_size,
                              hipStream_t stream) {
  const float* Q  = (const float*)d_in[0];
  const float* K  = (const float*)d_in[1];
  const float* V  = (const float*)d_in[2];
  const int*   VL = (const int*)d_in[3];
  float* O = (float*)d_out;

  const size_t kv_elems = (size_t)B_ * LK_ * D_;
  const size_t need = kv_elems * 2 * sizeof(unsigned short);
  if (ws_size >= need) {
    unsigned short* wsK = (unsigned short*)d_ws;
    unsigned short* wsV = wsK + kv_elems;
    prep_k<<<dim3(4096), dim3(256), 0, stream>>>(K, wsK);
    prep_v<<<dim3(512), dim3(256), 0, stream>>>(V, wsV);
    attn_fwd4<<<dim3(256), dim3(512), 0, stream>>>(Q, wsK, wsV, VL, O);
  } else {
    attn_fwd<<<dim3(512), dim3(256), 0, stream>>>(Q, K, V, VL, O);
  }
}